// Round 10
// baseline (145.250 us; speedup 1.0000x reference)
//
#include <hip/hip_runtime.h>
#include <math.h>

// GMM log-prob, S=1024 D=256 K=8 d=32. Target = dtype-faithful f32 numpy ref.
// cov is replicated BIT-EXACTLY in f32 per numpy's SSE3-baseline einsum
// (mul-round + 4-lane reversed add chains + hadd tree + f32 ridge). Do not
// perturb that ordering -- it is what makes the test pass (absmax 12 < 14.88).
//
// Round 10 = bisect round 9's failure:
//   gmm_precompute: VERBATIM round-8 code (known-passing, 79us).
//   gmm_main: 4 samples/thread, 256 blocks; i-loop unroll 2 (loads pipeline);
//             per-sample FP chain identical to round 8 -> same bits.
// ws layout (f32): Linv [2048*1024] | b [2048*32] | c [2048]  (~8.5 MB)

__global__ __launch_bounds__(128) void gmm_precompute(
    const float* __restrict__ mix,      // [256,8]
    const float* __restrict__ mean_p,   // [256,8,32]
    const float* __restrict__ cov_p,    // [256,8,32,32]
    const float* __restrict__ ds_stds,  // [256,32]
    float* __restrict__ LinvOut,        // [2048,32,32]
    float* __restrict__ bOut,           // [2048,32]
    float* __restrict__ cOut)           // [2048]
{
    const int tid  = threadIdx.x;
    const int sub  = tid >> 5;                 // 0..3 half-wave in block
    const int lane = tid & 31;
    const int pair = blockIdx.x * 4 + sub;     // 0..2047
    const int dd   = pair >> 3;
    const int k    = pair & 7;

    __shared__ double Csh[4][32][33];          // [sub][row][col]; col32 = invD
    __shared__ double Xsh[4][32][33];          // X = L^{-1}
    double (*C)[33] = Csh[sub];
    double (*X)[33] = Xsh[sub];

    // ---- P1: load W row `lane` (registers) ----
    float w[32];
    {
        const float4* wp = (const float4*)(cov_p + (size_t)pair * 1024 + lane * 32);
        #pragma unroll
        for (int q = 0; q < 8; ++q) {
            const float4 v = wp[q];
            w[4*q+0] = v.x; w[4*q+1] = v.y; w[4*q+2] = v.z; w[4*q+3] = v.w;
        }
    }

    // ---- P2: cov row in f32 (exact SSE3-emulated order) -> LDS f64 ----
    #pragma unroll 1
    for (int c = 0; c < 32; ++c) {
        float p[32];
        #pragma unroll
        for (int j = 0; j < 32; ++j)
            p[j] = __fmul_rn(w[j], __shfl(w[j], c, 32));
        float acc[4];
        #pragma unroll
        for (int l = 0; l < 4; ++l) {
            float t1 = p[12+l];
            t1 = __fadd_rn(p[8+l], t1);
            t1 = __fadd_rn(p[4+l], t1);
            t1 = __fadd_rn(p[0+l], t1);
            float t2 = __fadd_rn(p[28+l], t1);
            t2 = __fadd_rn(p[24+l], t2);
            t2 = __fadd_rn(p[20+l], t2);
            acc[l] = __fadd_rn(p[16+l], t2);
        }
        float s = __fadd_rn(__fadd_rn(acc[0], acc[1]), __fadd_rn(acc[2], acc[3]));
        if (c == lane) s = __fadd_rn(s, 1.0e-5f);
        C[lane][c] = (double)s;
    }

    // ---- P3: Cholesky (f64) in LDS; lane r owns row r. Grouped logdet. ----
    double hld = 0.0, prod = 1.0;
    #pragma unroll 1
    for (int c = 0; c < 32; ++c) {
        const double dv  = C[c][c];            // broadcast read
        const double dcc = sqrt(dv);
        prod *= dv;
        if ((c & 7) == 7) { hld += log(prod); prod = 1.0; }
        const double invd = 1.0 / dcc;
        double lrc = 0.0;
        if (lane > c) {
            lrc = C[lane][c] * invd;
            C[lane][c] = lrc;                  // L[lane][c]
        } else if (lane == c) {
            C[c][c]  = dcc;
            C[c][32] = invd;                   // stash 1/L[c][c]
        }
        if (lane > c) {
            #pragma unroll 1
            for (int c2 = c + 1; c2 <= lane; ++c2)
                C[lane][c2] = fma(-lrc, C[c2][c], C[lane][c2]);
        }
    }
    hld *= 0.5;   // dv = Lcc^2

    // ---- P4: forward substitution; lane = column of X = L^{-1} ----
    #pragma unroll 1
    for (int rr = 0; rr < 32; ++rr) {
        double s = (rr == lane) ? 1.0 : 0.0;
        #pragma unroll 1
        for (int j = 0; j < rr; ++j)
            s = fma(-C[rr][j], X[j][lane], s);  // C[rr][j] broadcast; X own col
        X[rr][lane] = s * C[rr][32];
    }

    // ---- P5a: write Linv f32 (coalesced: lanes span a row) ----
    #pragma unroll 1
    for (int rr = 0; rr < 32; ++rr)
        LinvOut[(size_t)pair * 1024 + rr * 32 + lane] = (float)X[rr][lane];

    // ---- P5b: b row `lane` = sum_j X[lane][j] * mu[j] (f64, asc j) ----
    const double mu_l = (double)mean_p[(size_t)pair * 32 + lane];
    double bacc = 0.0;
    #pragma unroll 1
    for (int j = 0; j < 32; ++j)
        bacc += X[lane][j] * __shfl(mu_l, j, 32);
    bOut[(size_t)pair * 32 + lane] = (float)bacc;

    // ---- P5c: c constant (product-butterfly for sum log std, 1 log) ----
    double sprod = (double)ds_stds[dd * 32 + lane];
    #pragma unroll
    for (int off = 16; off >= 1; off >>= 1)
        sprod *= __shfl_xor(sprod, off, 32);
    if (lane == 0) {
        const double lsd = log(sprod);
        const float* mrow = mix + dd * 8;
        double mx = (double)mrow[0];
        #pragma unroll
        for (int q = 1; q < 8; ++q) mx = fmax(mx, (double)mrow[q]);
        double se = 0.0;
        #pragma unroll
        for (int q = 0; q < 8; ++q) se += exp((double)mrow[q] - mx);
        const double logpi = (double)mrow[k] - mx - log(se);
        const double LOG2PI = 1.8378770664093454836;  // log(2*pi)
        cOut[pair] = (float)(logpi - hld - 16.0 * LOG2PI - lsd);
    }
}

// Heavy kernel (f32): 256 blocks x 256 threads, one dd per block, ALL 1024
// samples, 4 samples/thread (samples t, t+256, t+512, t+768). L broadcast
// reads amortized over 4 samples. Per-sample FP order identical to round 8.
__global__ __launch_bounds__(256) void gmm_main(
    const float* __restrict__ data,     // [1024,256,32]
    const float* __restrict__ ds_means, // [256,32]
    const float* __restrict__ ds_stds,  // [256,32]
    const float* __restrict__ Linv,     // [2048,32,32] f32
    const float* __restrict__ bvec,     // [2048,32] f32
    const float* __restrict__ cdk,      // [2048] f32
    float* __restrict__ out)            // [1024,256]
{
    const int dd = blockIdx.x;          // 0..255
    const int t  = threadIdx.x;

    __shared__ float Ls[8192];          // 32 KB
    __shared__ float bs[256];
    __shared__ float cs[8];
    __shared__ float mn[32];
    __shared__ float is[32];

    {
        const float4* Lp = (const float4*)(Linv + (size_t)dd * 8192);
        float4* Ld = (float4*)Ls;
        for (int e = t; e < 2048; e += 256) Ld[e] = Lp[e];
    }
    bs[t] = bvec[(size_t)dd * 256 + t];
    if (t < 8)  cs[t] = cdk[dd * 8 + t];
    if (t < 32) { mn[t] = ds_means[dd*32+t]; is[t] = 1.0f / ds_stds[dd*32+t]; }
    __syncthreads();

    float y[4][32];
    #pragma unroll
    for (int sg = 0; sg < 4; ++sg) {
        const float4* xp = (const float4*)(data + ((size_t)(sg*256 + t) * 256 + dd) * 32);
        #pragma unroll
        for (int q = 0; q < 8; ++q) {
            const float4 v = xp[q];
            const int j4 = 4 * q;
            y[sg][j4+0] = (v.x - mn[j4+0]) * is[j4+0];
            y[sg][j4+1] = (v.y - mn[j4+1]) * is[j4+1];
            y[sg][j4+2] = (v.z - mn[j4+2]) * is[j4+2];
            y[sg][j4+3] = (v.w - mn[j4+3]) * is[j4+3];
        }
    }

    float m0=-1e30f, e0=0.f, m1=-1e30f, e1=0.f;
    float m2=-1e30f, e2=0.f, m3=-1e30f, e3=0.f;

    #pragma unroll 1
    for (int kk = 0; kk < 8; ++kk) {
        float q0 = 0.f, q1 = 0.f, q2 = 0.f, q3 = 0.f;
        // unroll 2: two independent lrow loads in flight; q-accumulation
        // order across i unchanged (i, then i+1) -> bit-exact vs round 8.
        #pragma unroll 2
        for (int i = 0; i < 32; ++i) {
            const float4* Lr = (const float4*)&Ls[(kk * 32 + i) * 32];
            const float bv = bs[kk * 32 + i];
            float lrow[32];
            #pragma unroll
            for (int qq = 0; qq < 8; ++qq) {
                const float4 v = Lr[qq];
                lrow[4*qq+0] = v.x; lrow[4*qq+1] = v.y;
                lrow[4*qq+2] = v.z; lrow[4*qq+3] = v.w;
            }
            float za0 = -bv, za1 = -bv, za2 = -bv, za3 = -bv;
            float zb0 = 0.f, zb1 = 0.f, zb2 = 0.f, zb3 = 0.f;
            #pragma unroll
            for (int j = 0; j < 16; ++j) {
                const float l = lrow[j];
                za0 = fmaf(l, y[0][j], za0);
                za1 = fmaf(l, y[1][j], za1);
                za2 = fmaf(l, y[2][j], za2);
                za3 = fmaf(l, y[3][j], za3);
            }
            #pragma unroll
            for (int j = 16; j < 32; ++j) {
                const float l = lrow[j];
                zb0 = fmaf(l, y[0][j], zb0);
                zb1 = fmaf(l, y[1][j], zb1);
                zb2 = fmaf(l, y[2][j], zb2);
                zb3 = fmaf(l, y[3][j], zb3);
            }
            const float z0 = za0 + zb0;
            const float z1 = za1 + zb1;
            const float z2 = za2 + zb2;
            const float z3 = za3 + zb3;
            q0 = fmaf(z0, z0, q0);
            q1 = fmaf(z1, z1, q1);
            q2 = fmaf(z2, z2, q2);
            q3 = fmaf(z3, z3, q3);
        }
        const float a0 = cs[kk] - 0.5f * q0;
        const float a1 = cs[kk] - 0.5f * q1;
        const float a2 = cs[kk] - 0.5f * q2;
        const float a3 = cs[kk] - 0.5f * q3;
        const float nm0 = fmaxf(m0, a0); e0 = e0*expf(m0-nm0) + expf(a0-nm0); m0 = nm0;
        const float nm1 = fmaxf(m1, a1); e1 = e1*expf(m1-nm1) + expf(a1-nm1); m1 = nm1;
        const float nm2 = fmaxf(m2, a2); e2 = e2*expf(m2-nm2) + expf(a2-nm2); m2 = nm2;
        const float nm3 = fmaxf(m3, a3); e3 = e3*expf(m3-nm3) + expf(a3-nm3); m3 = nm3;
    }

    out[(size_t)(0*256 + t) * 256 + dd] = m0 + logf(e0);
    out[(size_t)(1*256 + t) * 256 + dd] = m1 + logf(e1);
    out[(size_t)(2*256 + t) * 256 + dd] = m2 + logf(e2);
    out[(size_t)(3*256 + t) * 256 + dd] = m3 + logf(e3);
}

extern "C" void kernel_launch(void* const* d_in, const int* in_sizes, int n_in,
                              void* d_out, int out_size, void* d_ws, size_t ws_size,
                              hipStream_t stream) {
    const float* data   = (const float*)d_in[0];   // [1024,256,32]
    const float* mix    = (const float*)d_in[1];   // [256,8]
    const float* mean_p = (const float*)d_in[2];   // [256,8,32]
    const float* cov_p  = (const float*)d_in[3];   // [256,8,32,32]
    const float* ds_m   = (const float*)d_in[4];   // [256,32]
    const float* ds_s   = (const float*)d_in[5];   // [256,32]
    float* out = (float*)d_out;

    float* Linv = (float*)d_ws;                 // 2048*1024 f32
    float* bvec = Linv + 2048 * 1024;           // 2048*32 f32
    float* cdk  = bvec + 2048 * 32;             // 2048 f32

    gmm_precompute<<<512, 128, 0, stream>>>(mix, mean_p, cov_p, ds_s,
                                            Linv, bvec, cdk);
    gmm_main<<<256, 256, 0, stream>>>(data, ds_m, ds_s, Linv, bvec, cdk, out);
}

// Round 11
// 143.398 us; speedup vs baseline: 1.0129x; 1.0129x over previous
//
#include <hip/hip_runtime.h>
#include <math.h>

// GMM log-prob, S=1024 D=256 K=8 d=32. Target = dtype-faithful f32 numpy ref.
// cov is replicated BIT-EXACTLY in f32 per numpy's SSE3-baseline einsum
// (mul-round + 4-lane reversed add chains + hadd tree + f32 ridge). Do not
// perturb that ordering -- it is what makes the test pass (absmax 12 < 14.88).
//
// Round 11 (scheduling-only changes, FP order preserved => bit-identical):
//  precompute: P3 inner loop -> UNIFORM bounds (c2<32, predicated) + unroll 4;
//    P4 j-loop unroll 4; P5b unroll 4. Pipelines the dependent LDS reads that
//    made P3/P4 ~60us of single-outstanding latency. No layout changes.
//  main: __launch_bounds__(256,1) -> 512-VGPR budget so y[4][32] stays in
//    registers (round-10's silent spill: VGPR capped at 128 = |y| alone).
// ws layout (f32): Linv [2048*1024] | b [2048*32] | c [2048]  (~8.5 MB)

__global__ __launch_bounds__(128) void gmm_precompute(
    const float* __restrict__ mix,      // [256,8]
    const float* __restrict__ mean_p,   // [256,8,32]
    const float* __restrict__ cov_p,    // [256,8,32,32]
    const float* __restrict__ ds_stds,  // [256,32]
    float* __restrict__ LinvOut,        // [2048,32,32]
    float* __restrict__ bOut,           // [2048,32]
    float* __restrict__ cOut)           // [2048]
{
    const int tid  = threadIdx.x;
    const int sub  = tid >> 5;                 // 0..3 half-wave in block
    const int lane = tid & 31;
    const int pair = blockIdx.x * 4 + sub;     // 0..2047
    const int dd   = pair >> 3;
    const int k    = pair & 7;

    __shared__ double Csh[4][32][33];          // [sub][row][col]; col32 = invD
    __shared__ double Xsh[4][32][33];          // X = L^{-1}
    double (*C)[33] = Csh[sub];
    double (*X)[33] = Xsh[sub];

    // ---- P1: load W row `lane` (registers) ----
    float w[32];
    {
        const float4* wp = (const float4*)(cov_p + (size_t)pair * 1024 + lane * 32);
        #pragma unroll
        for (int q = 0; q < 8; ++q) {
            const float4 v = wp[q];
            w[4*q+0] = v.x; w[4*q+1] = v.y; w[4*q+2] = v.z; w[4*q+3] = v.w;
        }
    }

    // ---- P2: cov row in f32 (exact SSE3-emulated order) -> LDS f64 ----
    #pragma unroll 1
    for (int c = 0; c < 32; ++c) {
        float p[32];
        #pragma unroll
        for (int j = 0; j < 32; ++j)
            p[j] = __fmul_rn(w[j], __shfl(w[j], c, 32));
        float acc[4];
        #pragma unroll
        for (int l = 0; l < 4; ++l) {
            float t1 = p[12+l];
            t1 = __fadd_rn(p[8+l], t1);
            t1 = __fadd_rn(p[4+l], t1);
            t1 = __fadd_rn(p[0+l], t1);
            float t2 = __fadd_rn(p[28+l], t1);
            t2 = __fadd_rn(p[24+l], t2);
            t2 = __fadd_rn(p[20+l], t2);
            acc[l] = __fadd_rn(p[16+l], t2);
        }
        float s = __fadd_rn(__fadd_rn(acc[0], acc[1]), __fadd_rn(acc[2], acc[3]));
        if (c == lane) s = __fadd_rn(s, 1.0e-5f);
        C[lane][c] = (double)s;
    }

    // ---- P3: Cholesky (f64) in LDS; lane r owns row r. Grouped logdet. ----
    // Inner loop has UNIFORM bounds (predicated body) so unroll-4 is clean:
    // per-iteration read/write sets are disjoint across lanes (reads col c,
    // writes cols >= c+1), so scheduling cannot create hazards.
    double hld = 0.0, prod = 1.0;
    #pragma unroll 1
    for (int c = 0; c < 32; ++c) {
        const double dv  = C[c][c];            // broadcast read
        const double dcc = sqrt(dv);
        prod *= dv;
        if ((c & 7) == 7) { hld += log(prod); prod = 1.0; }
        const double invd = 1.0 / dcc;
        double lrc = 0.0;
        if (lane > c) {
            lrc = C[lane][c] * invd;
            C[lane][c] = lrc;                  // L[lane][c]
        } else if (lane == c) {
            C[c][c]  = dcc;
            C[c][32] = invd;                   // stash 1/L[c][c]
        }
        #pragma unroll 4
        for (int c2 = c + 1; c2 < 32; ++c2) {
            if (lane >= c2)                    // == (lane > c && c2 <= lane)
                C[lane][c2] = fma(-lrc, C[c2][c], C[lane][c2]);
        }
    }
    hld *= 0.5;   // dv = Lcc^2

    // ---- P4: forward substitution; lane = column of X = L^{-1} ----
    // Bounds uniform; j-loop unroll 4 pipelines the two LDS reads per fma.
    // FP sequence per lane unchanged.
    #pragma unroll 1
    for (int rr = 0; rr < 32; ++rr) {
        double s = (rr == lane) ? 1.0 : 0.0;
        #pragma unroll 4
        for (int j = 0; j < rr; ++j)
            s = fma(-C[rr][j], X[j][lane], s);  // C[rr][j] broadcast; X own col
        X[rr][lane] = s * C[rr][32];
    }

    // ---- P5a: write Linv f32 (coalesced: lanes span a row) ----
    #pragma unroll 1
    for (int rr = 0; rr < 32; ++rr)
        LinvOut[(size_t)pair * 1024 + rr * 32 + lane] = (float)X[rr][lane];

    // ---- P5b: b row `lane` = sum_j X[lane][j] * mu[j] (f64, asc j) ----
    const double mu_l = (double)mean_p[(size_t)pair * 32 + lane];
    double bacc = 0.0;
    #pragma unroll 4
    for (int j = 0; j < 32; ++j)
        bacc += X[lane][j] * __shfl(mu_l, j, 32);
    bOut[(size_t)pair * 32 + lane] = (float)bacc;

    // ---- P5c: c constant (product-butterfly for sum log std, 1 log) ----
    double sprod = (double)ds_stds[dd * 32 + lane];
    #pragma unroll
    for (int off = 16; off >= 1; off >>= 1)
        sprod *= __shfl_xor(sprod, off, 32);
    if (lane == 0) {
        const double lsd = log(sprod);
        const float* mrow = mix + dd * 8;
        double mx = (double)mrow[0];
        #pragma unroll
        for (int q = 1; q < 8; ++q) mx = fmax(mx, (double)mrow[q]);
        double se = 0.0;
        #pragma unroll
        for (int q = 0; q < 8; ++q) se += exp((double)mrow[q] - mx);
        const double logpi = (double)mrow[k] - mx - log(se);
        const double LOG2PI = 1.8378770664093454836;  // log(2*pi)
        cOut[pair] = (float)(logpi - hld - 16.0 * LOG2PI - lsd);
    }
}

// Heavy kernel (f32): 256 blocks x 256 threads, one dd per block, ALL 1024
// samples, 4 samples/thread. __launch_bounds__(256,1): 512-VGPR budget so
// y[4][32] (128 VGPR) is register-resident (round-10 spilled at cap 128).
// Per-sample FP chain identical to round 8 -> bit-identical output.
__global__ __launch_bounds__(256, 1) void gmm_main(
    const float* __restrict__ data,     // [1024,256,32]
    const float* __restrict__ ds_means, // [256,32]
    const float* __restrict__ ds_stds,  // [256,32]
    const float* __restrict__ Linv,     // [2048,32,32] f32
    const float* __restrict__ bvec,     // [2048,32] f32
    const float* __restrict__ cdk,      // [2048] f32
    float* __restrict__ out)            // [1024,256]
{
    const int dd = blockIdx.x;          // 0..255
    const int t  = threadIdx.x;

    __shared__ float Ls[8192];          // 32 KB
    __shared__ float bs[256];
    __shared__ float cs[8];
    __shared__ float mn[32];
    __shared__ float is[32];

    {
        const float4* Lp = (const float4*)(Linv + (size_t)dd * 8192);
        float4* Ld = (float4*)Ls;
        for (int e = t; e < 2048; e += 256) Ld[e] = Lp[e];
    }
    bs[t] = bvec[(size_t)dd * 256 + t];
    if (t < 8)  cs[t] = cdk[dd * 8 + t];
    if (t < 32) { mn[t] = ds_means[dd*32+t]; is[t] = 1.0f / ds_stds[dd*32+t]; }
    __syncthreads();

    float y[4][32];
    #pragma unroll
    for (int sg = 0; sg < 4; ++sg) {
        const float4* xp = (const float4*)(data + ((size_t)(sg*256 + t) * 256 + dd) * 32);
        #pragma unroll
        for (int q = 0; q < 8; ++q) {
            const float4 v = xp[q];
            const int j4 = 4 * q;
            y[sg][j4+0] = (v.x - mn[j4+0]) * is[j4+0];
            y[sg][j4+1] = (v.y - mn[j4+1]) * is[j4+1];
            y[sg][j4+2] = (v.z - mn[j4+2]) * is[j4+2];
            y[sg][j4+3] = (v.w - mn[j4+3]) * is[j4+3];
        }
    }

    float m0=-1e30f, e0=0.f, m1=-1e30f, e1=0.f;
    float m2=-1e30f, e2=0.f, m3=-1e30f, e3=0.f;

    #pragma unroll 1
    for (int kk = 0; kk < 8; ++kk) {
        float q0 = 0.f, q1 = 0.f, q2 = 0.f, q3 = 0.f;
        // unroll 2: two independent lrow loads in flight; q-accumulation
        // order across i unchanged (i, then i+1) -> bit-exact vs round 8.
        #pragma unroll 2
        for (int i = 0; i < 32; ++i) {
            const float4* Lr = (const float4*)&Ls[(kk * 32 + i) * 32];
            const float bv = bs[kk * 32 + i];
            float lrow[32];
            #pragma unroll
            for (int qq = 0; qq < 8; ++qq) {
                const float4 v = Lr[qq];
                lrow[4*qq+0] = v.x; lrow[4*qq+1] = v.y;
                lrow[4*qq+2] = v.z; lrow[4*qq+3] = v.w;
            }
            float za0 = -bv, za1 = -bv, za2 = -bv, za3 = -bv;
            float zb0 = 0.f, zb1 = 0.f, zb2 = 0.f, zb3 = 0.f;
            #pragma unroll
            for (int j = 0; j < 16; ++j) {
                const float l = lrow[j];
                za0 = fmaf(l, y[0][j], za0);
                za1 = fmaf(l, y[1][j], za1);
                za2 = fmaf(l, y[2][j], za2);
                za3 = fmaf(l, y[3][j], za3);
            }
            #pragma unroll
            for (int j = 16; j < 32; ++j) {
                const float l = lrow[j];
                zb0 = fmaf(l, y[0][j], zb0);
                zb1 = fmaf(l, y[1][j], zb1);
                zb2 = fmaf(l, y[2][j], zb2);
                zb3 = fmaf(l, y[3][j], zb3);
            }
            const float z0 = za0 + zb0;
            const float z1 = za1 + zb1;
            const float z2 = za2 + zb2;
            const float z3 = za3 + zb3;
            q0 = fmaf(z0, z0, q0);
            q1 = fmaf(z1, z1, q1);
            q2 = fmaf(z2, z2, q2);
            q3 = fmaf(z3, z3, q3);
        }
        const float a0 = cs[kk] - 0.5f * q0;
        const float a1 = cs[kk] - 0.5f * q1;
        const float a2 = cs[kk] - 0.5f * q2;
        const float a3 = cs[kk] - 0.5f * q3;
        const float nm0 = fmaxf(m0, a0); e0 = e0*expf(m0-nm0) + expf(a0-nm0); m0 = nm0;
        const float nm1 = fmaxf(m1, a1); e1 = e1*expf(m1-nm1) + expf(a1-nm1); m1 = nm1;
        const float nm2 = fmaxf(m2, a2); e2 = e2*expf(m2-nm2) + expf(a2-nm2); m2 = nm2;
        const float nm3 = fmaxf(m3, a3); e3 = e3*expf(m3-nm3) + expf(a3-nm3); m3 = nm3;
    }

    out[(size_t)(0*256 + t) * 256 + dd] = m0 + logf(e0);
    out[(size_t)(1*256 + t) * 256 + dd] = m1 + logf(e1);
    out[(size_t)(2*256 + t) * 256 + dd] = m2 + logf(e2);
    out[(size_t)(3*256 + t) * 256 + dd] = m3 + logf(e3);
}

extern "C" void kernel_launch(void* const* d_in, const int* in_sizes, int n_in,
                              void* d_out, int out_size, void* d_ws, size_t ws_size,
                              hipStream_t stream) {
    const float* data   = (const float*)d_in[0];   // [1024,256,32]
    const float* mix    = (const float*)d_in[1];   // [256,8]
    const float* mean_p = (const float*)d_in[2];   // [256,8,32]
    const float* cov_p  = (const float*)d_in[3];   // [256,8,32,32]
    const float* ds_m   = (const float*)d_in[4];   // [256,32]
    const float* ds_s   = (const float*)d_in[5];   // [256,32]
    float* out = (float*)d_out;

    float* Linv = (float*)d_ws;                 // 2048*1024 f32
    float* bvec = Linv + 2048 * 1024;           // 2048*32 f32
    float* cdk  = bvec + 2048 * 32;             // 2048 f32

    gmm_precompute<<<512, 128, 0, stream>>>(mix, mean_p, cov_p, ds_s,
                                            Linv, bvec, cdk);
    gmm_main<<<256, 256, 0, stream>>>(data, ds_m, ds_s, Linv, bvec, cdk, out);
}